// Round 6
// baseline (259.306 us; speedup 1.0000x reference)
//
#include <hip/hip_runtime.h>
#include <stdint.h>

#define HW 4096
#define CCH 256
#define BPL (CCH * HW)          // per-batch plane elems
#define LSTR 264                // LDS Bs row stride in shorts (256+8 pad; 528B = 16B-aligned)

typedef __attribute__((ext_vector_type(8))) short short8;
typedef __attribute__((ext_vector_type(4))) float floatx4;
typedef unsigned short ushort_t;

__device__ inline ushort_t f2bf(float f) {
    union { float f; unsigned int u; } v; v.f = f;
    unsigned int r = v.u + 0x7FFFu + ((v.u >> 16) & 1u);   // RNE
    return (ushort_t)(r >> 16);
}
__device__ inline float bflo(unsigned u) {
    union { unsigned u; float f; } v; v.u = u << 16; return v.f;
}
__device__ inline float bfhi(unsigned u) {
    union { unsigned u; float f; } v; v.u = u & 0xFFFF0000u; return v.f;
}

// ---------------------------------------------------------------------------
// prep: weights->bf16, combined dw 9x9 (chunked layout), folded BN params.
// WcP[c][128]: slots 0..44 = dy 0..4 (dy*9+dx), slots 64..99 = dy 5..8.
__global__ void prep_kernel(
    const float* __restrict__ pre_w, const float* __restrict__ pw_w, const float* __restrict__ post_w,
    const float* __restrict__ g1, const float* __restrict__ b1, const float* __restrict__ m1, const float* __restrict__ v1,
    const float* __restrict__ g2, const float* __restrict__ b2, const float* __restrict__ m2, const float* __restrict__ v2,
    const float* __restrict__ g3, const float* __restrict__ b3, const float* __restrict__ m3, const float* __restrict__ v3,
    const float* __restrict__ w3d, const float* __restrict__ b3d,
    const float* __restrict__ w5d, const float* __restrict__ b5d,
    const float* __restrict__ w7d, const float* __restrict__ b7d,
    const float* __restrict__ w9d, const float* __restrict__ b9d,
    ushort_t* __restrict__ w1b, ushort_t* __restrict__ w2b, ushort_t* __restrict__ w3b,
    float* __restrict__ WcP, float* __restrict__ biasc,
    float* __restrict__ sc1, float* __restrict__ sh1,
    float* __restrict__ sc2, float* __restrict__ sh2,
    float* __restrict__ sc3, float* __restrict__ sh3)
{
    int c = blockIdx.x, t = threadIdx.x;
    w1b[c * 256 + t] = f2bf(pre_w[c * 256 + t]);
    w2b[c * 256 + t] = f2bf(pw_w[c * 256 + t]);
    w3b[c * 256 + t] = f2bf(post_w[c * 256 + t]);
    if (t < 128) {
        float val = 0.f;
        int dy = -1, dx = 0;
        if (t < 45) { dy = t / 9; dx = t % 9; }
        else if (t >= 64 && t < 100) { int i = t - 64; dy = 5 + i / 9; dx = i % 9; }
        if (dy >= 0) {
            val = w9d[c * 81 + dy * 9 + dx];
            if (dy >= 1 && dy <= 7 && dx >= 1 && dx <= 7) val += w7d[c * 49 + (dy - 1) * 7 + (dx - 1)];
            if (dy >= 2 && dy <= 6 && dx >= 2 && dx <= 6) val += w5d[c * 25 + (dy - 2) * 5 + (dx - 2)];
            if (dy >= 3 && dy <= 5 && dx >= 3 && dx <= 5) val += w3d[c * 9 + (dy - 3) * 3 + (dx - 3)];
            if (dy == 4 && dx == 4) val += 1.0f;  // identity branch
        }
        WcP[c * 128 + t] = val;
    }
    if (t == 128) { float s = g1[c] * rsqrtf(v1[c] + 1e-5f); sc1[c] = s; sh1[c] = b1[c] - m1[c] * s; }
    if (t == 129) { float s = g2[c] * rsqrtf(v2[c] + 1e-5f); sc2[c] = s; sh2[c] = b2[c] - m2[c] * s; }
    if (t == 130) { float s = g3[c] * rsqrtf(v3[c] + 1e-5f); sc3[c] = s; sh3[c] = b3[c] - m3[c] * s; }
    if (t == 131) biasc[c] = b3d[c] + b5d[c] + b7d[c] + b9d[c];
}

// ---------------------------------------------------------------------------
// LDS-staged MFMA 1x1 conv(s) on a 64-px tile, all 256 cout, K=256.
// 64-px tile -> Bs = 33 KB -> 3 blocks/CU (vs 2 at 128-px): better latency
// hiding for the channel-strided staging loads.
// MODE 0: in fp32 NCHW -> GEMM(wA)+bnA+relu -> bf16 NCHW       (conv1)
// MODE 1: in bf16 NCHW -> GEMM(wA)+bnA+relu -> t in LDS ->
//         GEMM(wB)+bnB+relu -> fp32 NCHW                       (conv2+conv3)
template <int MODE>
__global__ __launch_bounds__(256, 3) void conv_tile(
    const void* __restrict__ inp,
    const ushort_t* __restrict__ wA, const float* __restrict__ scA, const float* __restrict__ shA,
    const ushort_t* __restrict__ wB, const float* __restrict__ scB, const float* __restrict__ shB,
    void* __restrict__ outp)
{
    __shared__ __align__(16) ushort_t Bs[64 * LSTR];   // 33 KB
    const int tid = threadIdx.x;
    const int P0 = blockIdx.x * 64;           // global pixel base (never crosses batch)
    const int b = P0 >> 12, hw0 = P0 & 4095;
    unsigned int* Bsd = (unsigned int*)Bs;

    // ---- stage input tile [256 ch][64 px] -> Bs[px][ch] (ch-pairs packed as dwords)
    {
        const int c2 = tid & 127, ph = tid >> 7, px0 = ph * 32;
        if (MODE == 0) {
            const float* s0 = (const float*)inp + (size_t)b * BPL + (size_t)(2 * c2) * HW + hw0 + px0;
            const float* s1 = s0 + HW;
#pragma unroll
            for (int i = 0; i < 8; i++) {
                float4 v0 = *(const float4*)(s0 + 4 * i);
                float4 v1 = *(const float4*)(s1 + 4 * i);
                const int px = px0 + 4 * i;
                Bsd[(px + 0) * (LSTR / 2) + c2] = (unsigned)f2bf(v0.x) | ((unsigned)f2bf(v1.x) << 16);
                Bsd[(px + 1) * (LSTR / 2) + c2] = (unsigned)f2bf(v0.y) | ((unsigned)f2bf(v1.y) << 16);
                Bsd[(px + 2) * (LSTR / 2) + c2] = (unsigned)f2bf(v0.z) | ((unsigned)f2bf(v1.z) << 16);
                Bsd[(px + 3) * (LSTR / 2) + c2] = (unsigned)f2bf(v0.w) | ((unsigned)f2bf(v1.w) << 16);
            }
        } else {
            const ushort_t* s0 = (const ushort_t*)inp + (size_t)b * BPL + (size_t)(2 * c2) * HW + hw0 + px0;
            const ushort_t* s1 = s0 + HW;
#pragma unroll
            for (int i = 0; i < 4; i++) {
                union { uint4 v; ushort_t u[8]; } r0, r1;
                r0.v = *(const uint4*)(s0 + 8 * i);
                r1.v = *(const uint4*)(s1 + 8 * i);
                const int px = px0 + 8 * i;
#pragma unroll
                for (int j = 0; j < 8; j++)
                    Bsd[(px + j) * (LSTR / 2) + c2] = (unsigned)r0.u[j] | ((unsigned)r1.u[j] << 16);
            }
        }
    }
    __syncthreads();

    const int wave = tid >> 6, lane = tid & 63, quad = lane >> 4, L = lane & 15;
    const int coutw = wave * 64;

    floatx4 acc[4][4];

    // GEMM over K=256 (8 chunks of 32): A from global (L2-hot weights,
    // prefetched one chunk ahead), B from LDS.
    auto run_gemm = [&](const ushort_t* W) {
#pragma unroll
        for (int mt = 0; mt < 4; mt++)
#pragma unroll
            for (int nt = 0; nt < 4; nt++) acc[mt][nt] = (floatx4){0.f, 0.f, 0.f, 0.f};
        const ushort_t* Ab = W + (size_t)(coutw + L) * CCH + quad * 8;
        short8 Ac[4], An[4];
#pragma unroll
        for (int mt = 0; mt < 4; mt++) Ac[mt] = *(const short8*)(Ab + mt * 16 * CCH);
#pragma unroll
        for (int kt = 0; kt < 8; kt++) {
            if (kt < 7) {
#pragma unroll
                for (int mt = 0; mt < 4; mt++)
                    An[mt] = *(const short8*)(Ab + mt * 16 * CCH + (kt + 1) * 32);
            }
            short8 Bf[4];
#pragma unroll
            for (int nt = 0; nt < 4; nt++)
                Bf[nt] = *(const short8*)&Bs[(nt * 16 + L) * LSTR + kt * 32 + quad * 8];
#pragma unroll
            for (int mt = 0; mt < 4; mt++)
#pragma unroll
                for (int nt = 0; nt < 4; nt++)
                    acc[mt][nt] = __builtin_amdgcn_mfma_f32_16x16x32_bf16(
                        Ac[mt], Bf[nt], acc[mt][nt], 0, 0, 0);
            if (kt < 7) {
#pragma unroll
                for (int mt = 0; mt < 4; mt++) Ac[mt] = An[mt];
            }
        }
    };

    run_gemm(wA);

    if (MODE == 0) {
        // epilogue: bnA + relu -> bf16 NCHW
        ushort_t* outb = (ushort_t*)outp + (size_t)b * BPL + hw0;
#pragma unroll
        for (int mt = 0; mt < 4; mt++) {
#pragma unroll
            for (int r = 0; r < 4; r++) {
                const int cout = coutw + mt * 16 + quad * 4 + r;
                const float s = scA[cout], h0 = shA[cout];
#pragma unroll
                for (int nt = 0; nt < 4; nt++)
                    outb[(size_t)cout * HW + nt * 16 + L] =
                        f2bf(fmaxf(fmaf(acc[mt][nt][r], s, h0), 0.f));
            }
        }
    } else {
        // t = relu(bnA(.)) -> back into Bs (in-place; s fully consumed)
        __syncthreads();
#pragma unroll
        for (int mt = 0; mt < 4; mt++) {
            const int cout0 = coutw + mt * 16 + quad * 4;
            float sc4[4], sh4[4];
#pragma unroll
            for (int r = 0; r < 4; r++) { sc4[r] = scA[cout0 + r]; sh4[r] = shA[cout0 + r]; }
#pragma unroll
            for (int nt = 0; nt < 4; nt++) {
                const int px = nt * 16 + L;
                ushort4 pk;
                pk.x = f2bf(fmaxf(fmaf(acc[mt][nt][0], sc4[0], sh4[0]), 0.f));
                pk.y = f2bf(fmaxf(fmaf(acc[mt][nt][1], sc4[1], sh4[1]), 0.f));
                pk.z = f2bf(fmaxf(fmaf(acc[mt][nt][2], sc4[2], sh4[2]), 0.f));
                pk.w = f2bf(fmaxf(fmaf(acc[mt][nt][3], sc4[3], sh4[3]), 0.f));
                *(ushort4*)&Bs[px * LSTR + cout0] = pk;
            }
        }
        __syncthreads();
        run_gemm(wB);
        // epilogue: bnB + relu -> fp32 NCHW
        float* outb = (float*)outp + (size_t)b * BPL + hw0;
#pragma unroll
        for (int mt = 0; mt < 4; mt++) {
#pragma unroll
            for (int r = 0; r < 4; r++) {
                const int cout = coutw + mt * 16 + quad * 4 + r;
                const float s = scB[cout], h0 = shB[cout];
#pragma unroll
                for (int nt = 0; nt < 4; nt++)
                    outb[(size_t)cout * HW + nt * 16 + L] =
                        fmaxf(fmaf(acc[mt][nt][r], s, h0), 0.f);
            }
        }
    }
}

// ---------------------------------------------------------------------------
// Combined 9x9 depthwise (+identity, +summed bias), bf16 NCHW in/out.
// One block per (b,c) plane. LDS tile kept in *bf16* (10.4 KB): window reads
// are ds_read_b64 -> 16 distinct chunk-groups per 16-lane phase (group =
// (18*row + tx + j) mod 16, tx spans 0..15) -> conflict-free, and half the
// LDS traffic of the fp32 tile (R5: 1.3e7 SQ_LDS_BANK_CONFLICT from b128
// tx/tx+8 aliasing). Unpack to fp32 costs 12 VALU/window.
__global__ __launch_bounds__(256, 3) void dw_kernel(
    const ushort_t* __restrict__ h, const float* __restrict__ WcP,
    const float* __restrict__ biasc, ushort_t* __restrict__ out)
{
    const int bcp = blockIdx.x, c = bcp & 255;
    const size_t plane = (size_t)bcp * HW;
    __shared__ __align__(16) ushort_t tile[72 * 72];   // bf16, 10.4 KB
    unsigned* td = (unsigned*)tile;                    // [72][36] dwords
    const int tid = threadIdx.x;

    // zero halo borders: rows 0..3 & 68..71 (8x36 dwords) + side cols
    // (rows 4..67, dwords {0,1,34,35}) = 544 dwords, disjoint from interior.
    for (int f = tid; f < 544; f += 256) {
        int row, col;
        if (f < 288) { row = f / 36; if (row >= 4) row += 64; col = f % 36; }
        else { int f2 = f - 288; row = 4 + (f2 >> 2); int k = f2 & 3; col = (k < 2) ? k : 32 + k; }
        td[row * 36 + col] = 0u;
    }
    // interior: thread copies 32 contiguous bytes (16 bf16 px) of row r
    {
        const int r = tid >> 2, q = tid & 3;
        const ushort_t* src = h + plane + r * 64 + q * 16;
        uint4 a = *(const uint4*)src;
        uint4 bq = *(const uint4*)(src + 8);
        uint2* dst = (uint2*)(td + (r + 4) * 36 + 2 + q * 8);   // 8B-aligned
        dst[0] = make_uint2(a.x, a.y);
        dst[1] = make_uint2(a.z, a.w);
        dst[2] = make_uint2(bq.x, bq.y);
        dst[3] = make_uint2(bq.z, bq.w);
    }
    __syncthreads();

    const int tx = tid & 15, ty = tid >> 4;
    const int x0 = tx * 4, y0 = ty * 4;
    float acc[4][4];
#pragma unroll
    for (int i = 0; i < 4; i++)
#pragma unroll
        for (int j = 0; j < 4; j++) acc[i][j] = 0.f;

    const float* wp = WcP + c * 128;
    float wr[48];

    // chunk A: dy 0..4 (45 weights), rows y0+0..7
#pragma unroll
    for (int i = 0; i < 12; i++) *(float4*)&wr[4 * i] = *(const float4*)(wp + 4 * i);
#pragma unroll
    for (int r6 = 0; r6 < 8; r6++) {
        const ushort_t* rowp = &tile[(y0 + r6) * 72 + x0];
        uint2 a0 = *(const uint2*)rowp;
        uint2 a1 = *(const uint2*)(rowp + 4);
        uint2 a2 = *(const uint2*)(rowp + 8);
        float win[12];
        win[0] = bflo(a0.x); win[1] = bfhi(a0.x); win[2]  = bflo(a0.y); win[3]  = bfhi(a0.y);
        win[4] = bflo(a1.x); win[5] = bfhi(a1.x); win[6]  = bflo(a1.y); win[7]  = bfhi(a1.y);
        win[8] = bflo(a2.x); win[9] = bfhi(a2.x); win[10] = bflo(a2.y); win[11] = bfhi(a2.y);
#pragma unroll
        for (int yy = 0; yy < 4; yy++) {
            const int d = r6 - yy;
            if (d >= 0 && d <= 4) {
#pragma unroll
                for (int t = 0; t < 9; t++)
#pragma unroll
                    for (int j = 0; j < 4; j++)
                        acc[yy][j] = fmaf(wr[d * 9 + t], win[j + t], acc[yy][j]);
            }
        }
    }
    // chunk B: dy 5..8 (36 weights), rows y0+5..11
#pragma unroll
    for (int i = 0; i < 9; i++) *(float4*)&wr[4 * i] = *(const float4*)(wp + 64 + 4 * i);
#pragma unroll
    for (int r6 = 5; r6 < 12; r6++) {
        const ushort_t* rowp = &tile[(y0 + r6) * 72 + x0];
        uint2 a0 = *(const uint2*)rowp;
        uint2 a1 = *(const uint2*)(rowp + 4);
        uint2 a2 = *(const uint2*)(rowp + 8);
        float win[12];
        win[0] = bflo(a0.x); win[1] = bfhi(a0.x); win[2]  = bflo(a0.y); win[3]  = bfhi(a0.y);
        win[4] = bflo(a1.x); win[5] = bfhi(a1.x); win[6]  = bflo(a1.y); win[7]  = bfhi(a1.y);
        win[8] = bflo(a2.x); win[9] = bfhi(a2.x); win[10] = bflo(a2.y); win[11] = bfhi(a2.y);
#pragma unroll
        for (int yy = 0; yy < 4; yy++) {
            const int d = r6 - yy;
            if (d >= 5 && d <= 8) {
#pragma unroll
                for (int t = 0; t < 9; t++)
#pragma unroll
                    for (int j = 0; j < 4; j++)
                        acc[yy][j] = fmaf(wr[(d - 5) * 9 + t], win[j + t], acc[yy][j]);
            }
        }
    }

    const float bb = biasc[c];
#pragma unroll
    for (int yy = 0; yy < 4; yy++) {
        ushort4 o;
        o.x = f2bf(acc[yy][0] + bb);
        o.y = f2bf(acc[yy][1] + bb);
        o.z = f2bf(acc[yy][2] + bb);
        o.w = f2bf(acc[yy][3] + bb);
        *(ushort4*)&out[plane + (size_t)(y0 + yy) * 64 + x0] = o;
    }
}

// ---------------------------------------------------------------------------
extern "C" void kernel_launch(void* const* d_in, const int* in_sizes, int n_in,
                              void* d_out, int out_size, void* d_ws, size_t ws_size,
                              hipStream_t stream) {
    const float* x     = (const float*)d_in[0];
    const float* pre_w = (const float*)d_in[1];
    const float* bn1g  = (const float*)d_in[2];
    const float* bn1b  = (const float*)d_in[3];
    const float* bn1m  = (const float*)d_in[4];
    const float* bn1v  = (const float*)d_in[5];
    const float* dw3w  = (const float*)d_in[6];
    const float* dw3b  = (const float*)d_in[7];
    const float* dw5w  = (const float*)d_in[8];
    const float* dw5b  = (const float*)d_in[9];
    const float* dw7w  = (const float*)d_in[10];
    const float* dw7b  = (const float*)d_in[11];
    const float* dw9w  = (const float*)d_in[12];
    const float* dw9b  = (const float*)d_in[13];
    const float* pww   = (const float*)d_in[14];
    const float* bn2g  = (const float*)d_in[15];
    const float* bn2b  = (const float*)d_in[16];
    const float* bn2m  = (const float*)d_in[17];
    const float* bn2v  = (const float*)d_in[18];
    const float* postw = (const float*)d_in[19];
    const float* bn3g  = (const float*)d_in[20];
    const float* bn3b  = (const float*)d_in[21];
    const float* bn3m  = (const float*)d_in[22];
    const float* bn3v  = (const float*)d_in[23];

    // Buffers:
    //   h (bf16, 32 MiB)  -> d_out storage (dead before final fp32 write)
    //   s (bf16, 32 MiB)  -> ws[0:32Mi]
    //   aux               -> ws + 33 MiB
    char* wsb = (char*)d_ws;
    ushort_t* sbuf = (ushort_t*)wsb;
    ushort_t* hbuf = (ushort_t*)d_out;
    char* aux = wsb + (size_t)33 * 1024 * 1024;
    ushort_t* w1b = (ushort_t*)aux;
    ushort_t* w2b = w1b + 65536;
    ushort_t* w3b = w2b + 65536;
    float* WcP   = (float*)(w3b + 65536);      // 256*128 fp32
    float* biasc = WcP + 256 * 128;
    float* sc1 = biasc + 256;  float* sh1 = sc1 + 256;
    float* sc2 = sh1 + 256;    float* sh2 = sc2 + 256;
    float* sc3 = sh2 + 256;    float* sh3 = sc3 + 256;

    prep_kernel<<<256, 256, 0, stream>>>(
        pre_w, pww, postw,
        bn1g, bn1b, bn1m, bn1v, bn2g, bn2b, bn2m, bn2v, bn3g, bn3b, bn3m, bn3v,
        dw3w, dw3b, dw5w, dw5b, dw7w, dw7b, dw9w, dw9b,
        w1b, w2b, w3b, WcP, biasc, sc1, sh1, sc2, sh2, sc3, sh3);

    // conv1: x fp32 -> h bf16 NCHW (in d_out storage)
    conv_tile<0><<<1024, 256, 0, stream>>>(x, w1b, sc1, sh1,
                                           nullptr, nullptr, nullptr, hbuf);
    // dw: h -> s bf16 NCHW (in ws)
    dw_kernel<<<16 * CCH, 256, 0, stream>>>(hbuf, WcP, biasc, sbuf);
    // conv2+conv3 fused: s -> out fp32 NCHW (d_out; h dead)
    conv_tile<1><<<1024, 256, 0, stream>>>(sbuf, w2b, sc2, sh2,
                                           w3b, sc3, sh3, (float*)d_out);
}

// Round 7
// 245.633 us; speedup vs baseline: 1.0557x; 1.0557x over previous
//
#include <hip/hip_runtime.h>
#include <stdint.h>

#define HW 4096
#define CCH 256
#define BPL (CCH * HW)          // per-batch plane elems
#define LSTR 264                // LDS Bs row stride in shorts (256+8 pad; 528B = 16B-aligned)

typedef __attribute__((ext_vector_type(8))) short short8;
typedef __attribute__((ext_vector_type(4))) float floatx4;
typedef unsigned short ushort_t;

__device__ inline ushort_t f2bf(float f) {
    union { float f; unsigned int u; } v; v.f = f;
    unsigned int r = v.u + 0x7FFFu + ((v.u >> 16) & 1u);   // RNE
    return (ushort_t)(r >> 16);
}
__device__ inline float bflo(unsigned u) {
    union { unsigned u; float f; } v; v.u = u << 16; return v.f;
}
__device__ inline float bfhi(unsigned u) {
    union { unsigned u; float f; } v; v.u = u & 0xFFFF0000u; return v.f;
}

// ---------------------------------------------------------------------------
// prep: weights->bf16, combined dw 9x9 (chunked layout), folded BN params.
// WcP[c][128]: slots 0..44 = dy 0..4 (dy*9+dx), slots 64..99 = dy 5..8.
__global__ void prep_kernel(
    const float* __restrict__ pre_w, const float* __restrict__ pw_w, const float* __restrict__ post_w,
    const float* __restrict__ g1, const float* __restrict__ b1, const float* __restrict__ m1, const float* __restrict__ v1,
    const float* __restrict__ g2, const float* __restrict__ b2, const float* __restrict__ m2, const float* __restrict__ v2,
    const float* __restrict__ g3, const float* __restrict__ b3, const float* __restrict__ m3, const float* __restrict__ v3,
    const float* __restrict__ w3d, const float* __restrict__ b3d,
    const float* __restrict__ w5d, const float* __restrict__ b5d,
    const float* __restrict__ w7d, const float* __restrict__ b7d,
    const float* __restrict__ w9d, const float* __restrict__ b9d,
    ushort_t* __restrict__ w1b, ushort_t* __restrict__ w2b, ushort_t* __restrict__ w3b,
    float* __restrict__ WcP, float* __restrict__ biasc,
    float* __restrict__ sc1, float* __restrict__ sh1,
    float* __restrict__ sc2, float* __restrict__ sh2,
    float* __restrict__ sc3, float* __restrict__ sh3)
{
    int c = blockIdx.x, t = threadIdx.x;
    w1b[c * 256 + t] = f2bf(pre_w[c * 256 + t]);
    w2b[c * 256 + t] = f2bf(pw_w[c * 256 + t]);
    w3b[c * 256 + t] = f2bf(post_w[c * 256 + t]);
    if (t < 128) {
        float val = 0.f;
        int dy = -1, dx = 0;
        if (t < 45) { dy = t / 9; dx = t % 9; }
        else if (t >= 64 && t < 100) { int i = t - 64; dy = 5 + i / 9; dx = i % 9; }
        if (dy >= 0) {
            val = w9d[c * 81 + dy * 9 + dx];
            if (dy >= 1 && dy <= 7 && dx >= 1 && dx <= 7) val += w7d[c * 49 + (dy - 1) * 7 + (dx - 1)];
            if (dy >= 2 && dy <= 6 && dx >= 2 && dx <= 6) val += w5d[c * 25 + (dy - 2) * 5 + (dx - 2)];
            if (dy >= 3 && dy <= 5 && dx >= 3 && dx <= 5) val += w3d[c * 9 + (dy - 3) * 3 + (dx - 3)];
            if (dy == 4 && dx == 4) val += 1.0f;  // identity branch
        }
        WcP[c * 128 + t] = val;
    }
    if (t == 128) { float s = g1[c] * rsqrtf(v1[c] + 1e-5f); sc1[c] = s; sh1[c] = b1[c] - m1[c] * s; }
    if (t == 129) { float s = g2[c] * rsqrtf(v2[c] + 1e-5f); sc2[c] = s; sh2[c] = b2[c] - m2[c] * s; }
    if (t == 130) { float s = g3[c] * rsqrtf(v3[c] + 1e-5f); sc3[c] = s; sh3[c] = b3[c] - m3[c] * s; }
    if (t == 131) biasc[c] = b3d[c] + b5d[c] + b7d[c] + b9d[c];
}

// ---------------------------------------------------------------------------
// LDS-staged MFMA 1x1 conv(s) on a 64-px tile, all 256 cout, K=256.
// Staging is PIXEL-coalesced (R6 was channel-across-lanes: 64 cache lines
// per instruction -> latency-bound at 21% HBM). Lane reads px = pxq+16j of
// channel pair c2 = p*16+chunk; a wave instr = 4 contiguous 64B segments.
// LDS write bank = (4*pxq + c2) mod 32 -> all 32 banks 2-way across the
// wave = conflict-free. 33 KB LDS -> 4 blocks/CU; grid 1024 = exactly 4*256.
// MODE 0: in fp32 NCHW -> GEMM(wA)+bnA+relu -> bf16 NCHW       (conv1)
// MODE 1: in bf16 NCHW -> GEMM(wA)+bnA+relu -> t in LDS ->
//         GEMM(wB)+bnB+relu -> fp32 NCHW                       (conv2+conv3)
template <int MODE>
__global__ __launch_bounds__(256, 4) void conv_tile(
    const void* __restrict__ inp,
    const ushort_t* __restrict__ wA, const float* __restrict__ scA, const float* __restrict__ shA,
    const ushort_t* __restrict__ wB, const float* __restrict__ scB, const float* __restrict__ shB,
    void* __restrict__ outp)
{
    __shared__ __align__(16) ushort_t Bs[64 * LSTR];   // 33 KB
    const int tid = threadIdx.x;
    const int P0 = blockIdx.x * 64;           // global pixel base (never crosses batch)
    const int b = P0 >> 12, hw0 = P0 & 4095;
    unsigned int* Bsd = (unsigned int*)Bs;

    // ---- stage input tile [256 ch][64 px] -> Bs[px][ch] (ch-pairs as dwords)
    {
        const int pxq = tid & 15, chunk = tid >> 4;
        if (MODE == 0) {
            const float* base = (const float*)inp + (size_t)b * BPL + hw0 + pxq;
#pragma unroll
            for (int p = 0; p < 8; p++) {
                const int c2 = p * 16 + chunk;
                const float* s0 = base + (size_t)(2 * c2) * HW;
                const float* s1 = s0 + HW;
                float a0[4], a1[4];
#pragma unroll
                for (int j = 0; j < 4; j++) { a0[j] = s0[16 * j]; a1[j] = s1[16 * j]; }
#pragma unroll
                for (int j = 0; j < 4; j++)
                    Bsd[(pxq + 16 * j) * (LSTR / 2) + c2] =
                        (unsigned)f2bf(a0[j]) | ((unsigned)f2bf(a1[j]) << 16);
            }
        } else {
            const ushort_t* base = (const ushort_t*)inp + (size_t)b * BPL + hw0 + pxq;
#pragma unroll
            for (int p = 0; p < 8; p++) {
                const int c2 = p * 16 + chunk;
                const ushort_t* s0 = base + (size_t)(2 * c2) * HW;
                const ushort_t* s1 = s0 + HW;
                unsigned lo[4], hi[4];
#pragma unroll
                for (int j = 0; j < 4; j++) { lo[j] = s0[16 * j]; hi[j] = s1[16 * j]; }
#pragma unroll
                for (int j = 0; j < 4; j++)
                    Bsd[(pxq + 16 * j) * (LSTR / 2) + c2] = lo[j] | (hi[j] << 16);
            }
        }
    }
    __syncthreads();

    const int wave = tid >> 6, lane = tid & 63, quad = lane >> 4, L = lane & 15;
    const int coutw = wave * 64;

    floatx4 acc[4][4];

    // GEMM over K=256 (8 chunks of 32): A from global (L2-hot weights,
    // prefetched one chunk ahead), B from LDS.
    auto run_gemm = [&](const ushort_t* W) {
#pragma unroll
        for (int mt = 0; mt < 4; mt++)
#pragma unroll
            for (int nt = 0; nt < 4; nt++) acc[mt][nt] = (floatx4){0.f, 0.f, 0.f, 0.f};
        const ushort_t* Ab = W + (size_t)(coutw + L) * CCH + quad * 8;
        short8 Ac[4], An[4];
#pragma unroll
        for (int mt = 0; mt < 4; mt++) Ac[mt] = *(const short8*)(Ab + mt * 16 * CCH);
#pragma unroll
        for (int kt = 0; kt < 8; kt++) {
            if (kt < 7) {
#pragma unroll
                for (int mt = 0; mt < 4; mt++)
                    An[mt] = *(const short8*)(Ab + mt * 16 * CCH + (kt + 1) * 32);
            }
            short8 Bf[4];
#pragma unroll
            for (int nt = 0; nt < 4; nt++)
                Bf[nt] = *(const short8*)&Bs[(nt * 16 + L) * LSTR + kt * 32 + quad * 8];
#pragma unroll
            for (int mt = 0; mt < 4; mt++)
#pragma unroll
                for (int nt = 0; nt < 4; nt++)
                    acc[mt][nt] = __builtin_amdgcn_mfma_f32_16x16x32_bf16(
                        Ac[mt], Bf[nt], acc[mt][nt], 0, 0, 0);
            if (kt < 7) {
#pragma unroll
                for (int mt = 0; mt < 4; mt++) Ac[mt] = An[mt];
            }
        }
    };

    run_gemm(wA);

    if (MODE == 0) {
        // epilogue: bnA + relu -> bf16 NCHW
        ushort_t* outb = (ushort_t*)outp + (size_t)b * BPL + hw0;
#pragma unroll
        for (int mt = 0; mt < 4; mt++) {
#pragma unroll
            for (int r = 0; r < 4; r++) {
                const int cout = coutw + mt * 16 + quad * 4 + r;
                const float s = scA[cout], h0 = shA[cout];
#pragma unroll
                for (int nt = 0; nt < 4; nt++)
                    outb[(size_t)cout * HW + nt * 16 + L] =
                        f2bf(fmaxf(fmaf(acc[mt][nt][r], s, h0), 0.f));
            }
        }
    } else {
        // t = relu(bnA(.)) -> back into Bs (in-place; s fully consumed)
        __syncthreads();
#pragma unroll
        for (int mt = 0; mt < 4; mt++) {
            const int cout0 = coutw + mt * 16 + quad * 4;
            float sc4[4], sh4[4];
#pragma unroll
            for (int r = 0; r < 4; r++) { sc4[r] = scA[cout0 + r]; sh4[r] = shA[cout0 + r]; }
#pragma unroll
            for (int nt = 0; nt < 4; nt++) {
                const int px = nt * 16 + L;
                ushort4 pk;
                pk.x = f2bf(fmaxf(fmaf(acc[mt][nt][0], sc4[0], sh4[0]), 0.f));
                pk.y = f2bf(fmaxf(fmaf(acc[mt][nt][1], sc4[1], sh4[1]), 0.f));
                pk.z = f2bf(fmaxf(fmaf(acc[mt][nt][2], sc4[2], sh4[2]), 0.f));
                pk.w = f2bf(fmaxf(fmaf(acc[mt][nt][3], sc4[3], sh4[3]), 0.f));
                *(ushort4*)&Bs[px * LSTR + cout0] = pk;
            }
        }
        __syncthreads();
        run_gemm(wB);
        // epilogue: bnB + relu -> fp32 NCHW
        float* outb = (float*)outp + (size_t)b * BPL + hw0;
#pragma unroll
        for (int mt = 0; mt < 4; mt++) {
#pragma unroll
            for (int r = 0; r < 4; r++) {
                const int cout = coutw + mt * 16 + quad * 4 + r;
                const float s = scB[cout], h0 = shB[cout];
#pragma unroll
                for (int nt = 0; nt < 4; nt++)
                    outb[(size_t)cout * HW + nt * 16 + L] =
                        fmaxf(fmaf(acc[mt][nt][r], s, h0), 0.f);
            }
        }
    }
}

// ---------------------------------------------------------------------------
// Combined 9x9 depthwise (+identity, +summed bias), bf16 NCHW in/out.
// One block per (b,c) plane. LDS tile in bf16 (10.4 KB): window reads are
// ds_read_b64, conflict-free; unpack to fp32 in VALU.
__global__ __launch_bounds__(256, 3) void dw_kernel(
    const ushort_t* __restrict__ h, const float* __restrict__ WcP,
    const float* __restrict__ biasc, ushort_t* __restrict__ out)
{
    const int bcp = blockIdx.x, c = bcp & 255;
    const size_t plane = (size_t)bcp * HW;
    __shared__ __align__(16) ushort_t tile[72 * 72];   // bf16, 10.4 KB
    unsigned* td = (unsigned*)tile;                    // [72][36] dwords
    const int tid = threadIdx.x;

    // zero halo borders: rows 0..3 & 68..71 (8x36 dwords) + side cols
    // (rows 4..67, dwords {0,1,34,35}) = 544 dwords, disjoint from interior.
    for (int f = tid; f < 544; f += 256) {
        int row, col;
        if (f < 288) { row = f / 36; if (row >= 4) row += 64; col = f % 36; }
        else { int f2 = f - 288; row = 4 + (f2 >> 2); int k = f2 & 3; col = (k < 2) ? k : 32 + k; }
        td[row * 36 + col] = 0u;
    }
    // interior: thread copies 32 contiguous bytes (16 bf16 px) of row r
    {
        const int r = tid >> 2, q = tid & 3;
        const ushort_t* src = h + plane + r * 64 + q * 16;
        uint4 a = *(const uint4*)src;
        uint4 bq = *(const uint4*)(src + 8);
        uint2* dst = (uint2*)(td + (r + 4) * 36 + 2 + q * 8);   // 8B-aligned
        dst[0] = make_uint2(a.x, a.y);
        dst[1] = make_uint2(a.z, a.w);
        dst[2] = make_uint2(bq.x, bq.y);
        dst[3] = make_uint2(bq.z, bq.w);
    }
    __syncthreads();

    const int tx = tid & 15, ty = tid >> 4;
    const int x0 = tx * 4, y0 = ty * 4;
    float acc[4][4];
#pragma unroll
    for (int i = 0; i < 4; i++)
#pragma unroll
        for (int j = 0; j < 4; j++) acc[i][j] = 0.f;

    const float* wp = WcP + c * 128;
    float wr[48];

    // chunk A: dy 0..4 (45 weights), rows y0+0..7
#pragma unroll
    for (int i = 0; i < 12; i++) *(float4*)&wr[4 * i] = *(const float4*)(wp + 4 * i);
#pragma unroll
    for (int r6 = 0; r6 < 8; r6++) {
        const ushort_t* rowp = &tile[(y0 + r6) * 72 + x0];
        uint2 a0 = *(const uint2*)rowp;
        uint2 a1 = *(const uint2*)(rowp + 4);
        uint2 a2 = *(const uint2*)(rowp + 8);
        float win[12];
        win[0] = bflo(a0.x); win[1] = bfhi(a0.x); win[2]  = bflo(a0.y); win[3]  = bfhi(a0.y);
        win[4] = bflo(a1.x); win[5] = bfhi(a1.x); win[6]  = bflo(a1.y); win[7]  = bfhi(a1.y);
        win[8] = bflo(a2.x); win[9] = bfhi(a2.x); win[10] = bflo(a2.y); win[11] = bfhi(a2.y);
#pragma unroll
        for (int yy = 0; yy < 4; yy++) {
            const int d = r6 - yy;
            if (d >= 0 && d <= 4) {
#pragma unroll
                for (int t = 0; t < 9; t++)
#pragma unroll
                    for (int j = 0; j < 4; j++)
                        acc[yy][j] = fmaf(wr[d * 9 + t], win[j + t], acc[yy][j]);
            }
        }
    }
    // chunk B: dy 5..8 (36 weights), rows y0+5..11
#pragma unroll
    for (int i = 0; i < 9; i++) *(float4*)&wr[4 * i] = *(const float4*)(wp + 64 + 4 * i);
#pragma unroll
    for (int r6 = 5; r6 < 12; r6++) {
        const ushort_t* rowp = &tile[(y0 + r6) * 72 + x0];
        uint2 a0 = *(const uint2*)rowp;
        uint2 a1 = *(const uint2*)(rowp + 4);
        uint2 a2 = *(const uint2*)(rowp + 8);
        float win[12];
        win[0] = bflo(a0.x); win[1] = bfhi(a0.x); win[2]  = bflo(a0.y); win[3]  = bfhi(a0.y);
        win[4] = bflo(a1.x); win[5] = bfhi(a1.x); win[6]  = bflo(a1.y); win[7]  = bfhi(a1.y);
        win[8] = bflo(a2.x); win[9] = bfhi(a2.x); win[10] = bflo(a2.y); win[11] = bfhi(a2.y);
#pragma unroll
        for (int yy = 0; yy < 4; yy++) {
            const int d = r6 - yy;
            if (d >= 5 && d <= 8) {
#pragma unroll
                for (int t = 0; t < 9; t++)
#pragma unroll
                    for (int j = 0; j < 4; j++)
                        acc[yy][j] = fmaf(wr[(d - 5) * 9 + t], win[j + t], acc[yy][j]);
            }
        }
    }

    const float bb = biasc[c];
#pragma unroll
    for (int yy = 0; yy < 4; yy++) {
        ushort4 o;
        o.x = f2bf(acc[yy][0] + bb);
        o.y = f2bf(acc[yy][1] + bb);
        o.z = f2bf(acc[yy][2] + bb);
        o.w = f2bf(acc[yy][3] + bb);
        *(ushort4*)&out[plane + (size_t)(y0 + yy) * 64 + x0] = o;
    }
}

// ---------------------------------------------------------------------------
extern "C" void kernel_launch(void* const* d_in, const int* in_sizes, int n_in,
                              void* d_out, int out_size, void* d_ws, size_t ws_size,
                              hipStream_t stream) {
    const float* x     = (const float*)d_in[0];
    const float* pre_w = (const float*)d_in[1];
    const float* bn1g  = (const float*)d_in[2];
    const float* bn1b  = (const float*)d_in[3];
    const float* bn1m  = (const float*)d_in[4];
    const float* bn1v  = (const float*)d_in[5];
    const float* dw3w  = (const float*)d_in[6];
    const float* dw3b  = (const float*)d_in[7];
    const float* dw5w  = (const float*)d_in[8];
    const float* dw5b  = (const float*)d_in[9];
    const float* dw7w  = (const float*)d_in[10];
    const float* dw7b  = (const float*)d_in[11];
    const float* dw9w  = (const float*)d_in[12];
    const float* dw9b  = (const float*)d_in[13];
    const float* pww   = (const float*)d_in[14];
    const float* bn2g  = (const float*)d_in[15];
    const float* bn2b  = (const float*)d_in[16];
    const float* bn2m  = (const float*)d_in[17];
    const float* bn2v  = (const float*)d_in[18];
    const float* postw = (const float*)d_in[19];
    const float* bn3g  = (const float*)d_in[20];
    const float* bn3b  = (const float*)d_in[21];
    const float* bn3m  = (const float*)d_in[22];
    const float* bn3v  = (const float*)d_in[23];

    // Buffers:
    //   h (bf16, 32 MiB)  -> d_out storage (dead before final fp32 write)
    //   s (bf16, 32 MiB)  -> ws[0:32Mi]
    //   aux               -> ws + 33 MiB
    char* wsb = (char*)d_ws;
    ushort_t* sbuf = (ushort_t*)wsb;
    ushort_t* hbuf = (ushort_t*)d_out;
    char* aux = wsb + (size_t)33 * 1024 * 1024;
    ushort_t* w1b = (ushort_t*)aux;
    ushort_t* w2b = w1b + 65536;
    ushort_t* w3b = w2b + 65536;
    float* WcP   = (float*)(w3b + 65536);      // 256*128 fp32
    float* biasc = WcP + 256 * 128;
    float* sc1 = biasc + 256;  float* sh1 = sc1 + 256;
    float* sc2 = sh1 + 256;    float* sh2 = sc2 + 256;
    float* sc3 = sh2 + 256;    float* sh3 = sc3 + 256;

    prep_kernel<<<256, 256, 0, stream>>>(
        pre_w, pww, postw,
        bn1g, bn1b, bn1m, bn1v, bn2g, bn2b, bn2m, bn2v, bn3g, bn3b, bn3m, bn3v,
        dw3w, dw3b, dw5w, dw5b, dw7w, dw7b, dw9w, dw9b,
        w1b, w2b, w3b, WcP, biasc, sc1, sh1, sc2, sh2, sc3, sh3);

    // conv1: x fp32 -> h bf16 NCHW (in d_out storage)
    conv_tile<0><<<1024, 256, 0, stream>>>(x, w1b, sc1, sh1,
                                           nullptr, nullptr, nullptr, hbuf);
    // dw: h -> s bf16 NCHW (in ws)
    dw_kernel<<<16 * CCH, 256, 0, stream>>>(hbuf, WcP, biasc, sbuf);
    // conv2+conv3 fused: s -> out fp32 NCHW (d_out; h dead)
    conv_tile<1><<<1024, 256, 0, stream>>>(sbuf, w2b, sc2, sh2,
                                           w3b, sc3, sh3, (float*)d_out);
}